// Round 2
// baseline (4770.136 us; speedup 1.0000x reference)
//
#include <hip/hip_runtime.h>
#include <hip/hip_bf16.h>

#define V_     32000
#define NSEG_  2
#define MAXLEN_ 512
#define D_     768
#define H_     12
#define HS_    64
#define B_     16
#define T_     512
#define NMASK_ 20
#define LN_EPS_ 1e-5f

typedef __hip_bfloat16 bf16;

__device__ __forceinline__ float b2f(bf16 x) { return __bfloat162float(x); }

// ---------------- Kernel 1: embedding gather + LayerNorm ----------------
// grid = B*T blocks, 256 threads. x[row*D + j] (f32)
__global__ void k_embed_ln(const int* __restrict__ seq, const int* __restrict__ seg,
                           const float* __restrict__ tok, const float* __restrict__ sege,
                           const float* __restrict__ pos, const float* __restrict__ g,
                           const float* __restrict__ bb, float* __restrict__ x) {
    int row = blockIdx.x;          // b*T + t
    int t = row % T_;
    int tid = threadIdx.x;
    __shared__ float sbuf[D_];
    __shared__ float wsum[4], wsq[4];

    int sidx = seq[row];
    int gidx = seg[row];

    float lsum = 0.f, lsq = 0.f;
    for (int j = tid; j < D_; j += 256) {
        float e = tok[(size_t)sidx * D_ + j] + sege[(size_t)gidx * D_ + j] + pos[(size_t)t * D_ + j];
        sbuf[j] = e;
        lsum += e;
        lsq  += e * e;
    }
    #pragma unroll
    for (int o = 32; o > 0; o >>= 1) {
        lsum += __shfl_down(lsum, o);
        lsq  += __shfl_down(lsq, o);
    }
    if ((tid & 63) == 0) { wsum[tid >> 6] = lsum; wsq[tid >> 6] = lsq; }
    __syncthreads();
    float s  = wsum[0] + wsum[1] + wsum[2] + wsum[3];
    float sq = wsq[0] + wsq[1] + wsq[2] + wsq[3];
    float mean = s * (1.0f / D_);
    float var  = sq * (1.0f / D_) - mean * mean;
    float rstd = rsqrtf(var + LN_EPS_);
    for (int j = tid; j < D_; j += 256) {
        x[(size_t)row * D_ + j] = (sbuf[j] - mean) * rstd * g[j] + bb[j];
    }
}

// ---------------- Kernel 2: QKV projections ----------------
// grid = B*T blocks, 256 threads (4 waves). q/k/v layout: [(b*H+h)*T + t]*HS + s (bf16)
__global__ void k_qkv(const float* __restrict__ x,
                      const float* __restrict__ Wq, const float* __restrict__ Wk,
                      const float* __restrict__ Wv,
                      bf16* __restrict__ q, bf16* __restrict__ k, bf16* __restrict__ v) {
    int row = blockIdx.x;       // b*T + t
    int b = row / T_, t = row % T_;
    __shared__ float xl[D_];
    for (int j = threadIdx.x; j < D_; j += 256) xl[j] = x[(size_t)row * D_ + j];
    __syncthreads();

    int s   = threadIdx.x & 63;
    int grp = threadIdx.x >> 6;     // 0..3
    for (int m = grp; m < 3 * H_; m += 4) {
        int h = m / 3, which = m % 3;
        const float* W = (which == 0) ? Wq : (which == 1) ? Wk : Wv;
        const float* Wh = W + (size_t)h * D_ * HS_;
        float acc = 0.f;
        #pragma unroll 4
        for (int d = 0; d < D_; ++d) acc += xl[d] * Wh[(size_t)d * HS_ + s];
        bf16* out = (which == 0) ? q : (which == 1) ? k : v;
        out[((size_t)(b * H_ + h) * T_ + t) * HS_ + s] = __float2bfloat16(acc);
    }
}

// ---------------- Kernel 3: attention (one wave per (b,h,t)) ----------------
// x2[(b*T+t)*D + h*HS + s] (f32)
__global__ void k_attn(const bf16* __restrict__ q, const bf16* __restrict__ k,
                       const bf16* __restrict__ v, const int* __restrict__ attn_mask,
                       float* __restrict__ x2) {
    int idx = blockIdx.x;           // (b*H + h)*T + t
    int t  = idx % T_;
    int bh = idx / T_;
    int h  = bh % H_;
    int b  = bh / H_;
    int lane = threadIdx.x;         // 0..63

    __shared__ float qs[HS_];
    __shared__ float p[T_];

    const bf16* qrow = q + ((size_t)bh * T_ + t) * HS_;
    qs[lane] = b2f(qrow[lane]);
    __syncthreads();

    bool masked = (attn_mask[b * T_ + t] == 0);
    const bf16* kb = k + (size_t)bh * T_ * HS_;

    float sc[8];
    float mx = -1e30f;
    #pragma unroll
    for (int i = 0; i < 8; ++i) {
        int u = i * 64 + lane;
        const bf16* krow = kb + (size_t)u * HS_;
        float acc = 0.f;
        #pragma unroll 8
        for (int ss = 0; ss < HS_; ++ss) acc += qs[ss] * b2f(krow[ss]);
        sc[i] = masked ? -1e-11f : acc * 0.125f;   // HS^-0.5 = 0.125
        mx = fmaxf(mx, sc[i]);
    }
    #pragma unroll
    for (int o = 32; o > 0; o >>= 1) mx = fmaxf(mx, __shfl_xor(mx, o));
    float lsum = 0.f;
    #pragma unroll
    for (int i = 0; i < 8; ++i) { sc[i] = expf(sc[i] - mx); lsum += sc[i]; }
    #pragma unroll
    for (int o = 32; o > 0; o >>= 1) lsum += __shfl_xor(lsum, o);
    float inv = 1.0f / lsum;
    #pragma unroll
    for (int i = 0; i < 8; ++i) p[i * 64 + lane] = sc[i] * inv;
    __syncthreads();

    // out[s] = sum_u p[u] * v[u, s];  lane = s
    const bf16* vb = v + (size_t)bh * T_ * HS_;
    float acc = 0.f;
    for (int u = 0; u < T_; ++u) acc += p[u] * b2f(vb[(size_t)u * HS_ + lane]);
    x2[((size_t)b * T_ + t) * D_ + h * HS_ + lane] = acc;
}

// ---------------- Kernel 4: LM head ----------------
// grid (320, 125): x-fast over rows so consecutive blocks share the W_lm tile in L2.
__global__ void k_lm(const float* __restrict__ x2, const int* __restrict__ masked_pos,
                     const float* __restrict__ Wlm, const float* __restrict__ blm,
                     float* __restrict__ out) {
    int r  = blockIdx.x;            // 0..B*NMASK-1
    int vt = blockIdx.y;            // 0..124
    int b = r / NMASK_, m = r % NMASK_;
    int t = masked_pos[b * NMASK_ + m];

    __shared__ float xl[D_];
    for (int j = threadIdx.x; j < D_; j += 256)
        xl[j] = x2[((size_t)b * T_ + t) * D_ + j];
    __syncthreads();

    int vv = vt * 256 + threadIdx.x;
    float acc = blm[vv];
    const float* Wcol = Wlm + vv;
    #pragma unroll 4
    for (int d = 0; d < D_; ++d) acc += xl[d] * Wcol[(size_t)d * V_];
    out[(size_t)r * V_ + vv] = acc;
}

// ---------------- Kernel 5: classifier head ----------------
__global__ void k_cls(const float* __restrict__ x2, const float* __restrict__ Wc,
                      const float* __restrict__ bc, float* __restrict__ out) {
    int i = threadIdx.x;
    if (i >= B_ * 2) return;
    int b = i >> 1, c = i & 1;
    float acc = bc[c];
    for (int d = 0; d < D_; ++d)
        acc += x2[(size_t)b * T_ * D_ + d] * Wc[d * 2 + c];
    out[i] = acc;
}

extern "C" void kernel_launch(void* const* d_in, const int* in_sizes, int n_in,
                              void* d_out, int out_size, void* d_ws, size_t ws_size,
                              hipStream_t stream) {
    const int* seq        = (const int*)d_in[0];
    const int* seg        = (const int*)d_in[1];
    const int* attn_mask  = (const int*)d_in[2];
    const int* masked_pos = (const int*)d_in[3];
    const float* tok  = (const float*)d_in[4];
    const float* sege = (const float*)d_in[5];
    const float* pos  = (const float*)d_in[6];
    const float* ln_g = (const float*)d_in[7];
    const float* ln_b = (const float*)d_in[8];
    const float* Wq   = (const float*)d_in[9];
    const float* Wk   = (const float*)d_in[10];
    const float* Wv   = (const float*)d_in[11];
    const float* Wlm  = (const float*)d_in[12];
    const float* blm  = (const float*)d_in[13];
    const float* Wc   = (const float*)d_in[14];
    const float* bc   = (const float*)d_in[15];

    float* out_lm  = (float*)d_out;                       // [B, NMASK, V]
    float* out_cls = out_lm + (size_t)B_ * NMASK_ * V_;   // [B, 2]

    const size_t NTOK = (size_t)B_ * T_;                  // 8192
    const size_t XSZ  = NTOK * D_;                        // 6,291,456
    float* ws = (float*)d_ws;
    float* x  = ws;                // f32, 25.2 MB
    float* x2 = ws + XSZ;          // f32, 25.2 MB
    bf16*  q  = (bf16*)(ws + 2 * XSZ);
    bf16*  k  = q + XSZ;
    bf16*  v  = k + XSZ;           // qkv bf16, 37.8 MB; total ws use ~88 MB

    k_embed_ln<<<B_ * T_, 256, 0, stream>>>(seq, seg, tok, sege, pos, ln_g, ln_b, x);
    k_qkv<<<B_ * T_, 256, 0, stream>>>(x, Wq, Wk, Wv, q, k, v);
    k_attn<<<B_ * H_ * T_, 64, 0, stream>>>(q, k, v, attn_mask, x2);
    k_lm<<<dim3(B_ * NMASK_, V_ / 256), 256, 0, stream>>>(x2, masked_pos, Wlm, blm, out_lm);
    k_cls<<<1, 64, 0, stream>>>(x2, Wc, bc, out_cls);
}

// Round 3
// 1629.692 us; speedup vs baseline: 2.9270x; 2.9270x over previous
//
#include <hip/hip_runtime.h>
#include <hip/hip_bf16.h>

#define V_     32000
#define NSEG_  2
#define MAXLEN_ 512
#define D_     768
#define H_     12
#define HS_    64
#define B_     16
#define T_     512
#define NMASK_ 20
#define LN_EPS_ 1e-5f

typedef __hip_bfloat16 bf16;
typedef unsigned short ushortT;
typedef __attribute__((ext_vector_type(8))) short short8;
typedef __attribute__((ext_vector_type(4))) float f32x4;
typedef __attribute__((ext_vector_type(4))) unsigned int u32x4;

__device__ __forceinline__ float b2f(bf16 x) { return __bfloat162float(x); }
__device__ __forceinline__ ushortT f2bu(float f) {
    bf16 h = __float2bfloat16(f);
    return *reinterpret_cast<ushortT*>(&h);
}

// ---------------- Kernel 1: embedding gather + LayerNorm -> xb (bf16) ----------------
__global__ void k_embed_ln(const int* __restrict__ seq, const int* __restrict__ seg,
                           const float* __restrict__ tok, const float* __restrict__ sege,
                           const float* __restrict__ pos, const float* __restrict__ g,
                           const float* __restrict__ bb, ushortT* __restrict__ xb) {
    int row = blockIdx.x;          // b*T + t
    int t = row % T_;
    int tid = threadIdx.x;
    __shared__ float sbuf[D_];
    __shared__ float wsum[4], wsq[4];

    int sidx = seq[row];
    int gidx = seg[row];

    float lsum = 0.f, lsq = 0.f;
    for (int j = tid; j < D_; j += 256) {
        float e = tok[(size_t)sidx * D_ + j] + sege[(size_t)gidx * D_ + j] + pos[(size_t)t * D_ + j];
        sbuf[j] = e;
        lsum += e;
        lsq  += e * e;
    }
    #pragma unroll
    for (int o = 32; o > 0; o >>= 1) {
        lsum += __shfl_down(lsum, o);
        lsq  += __shfl_down(lsq, o);
    }
    if ((tid & 63) == 0) { wsum[tid >> 6] = lsum; wsq[tid >> 6] = lsq; }
    __syncthreads();
    float s  = wsum[0] + wsum[1] + wsum[2] + wsum[3];
    float sq = wsq[0] + wsq[1] + wsq[2] + wsq[3];
    float mean = s * (1.0f / D_);
    float var  = sq * (1.0f / D_) - mean * mean;
    float rstd = rsqrtf(var + LN_EPS_);
    for (int j = tid; j < D_; j += 256) {
        xb[(size_t)row * D_ + j] = f2bu((sbuf[j] - mean) * rstd * g[j] + bb[j]);
    }
}

// ---------------- Prep: WcatT[n][k] bf16, n = which*768 + h*64 + s ----------------
// grid 36 blocks (which*12+h), 256 threads
__global__ void k_prep_wqkv(const float* __restrict__ Wq, const float* __restrict__ Wk,
                            const float* __restrict__ Wv, ushortT* __restrict__ Wt) {
    int blk = blockIdx.x;
    int which = blk / H_, h = blk % H_;
    const float* W = (which == 0) ? Wq : (which == 1) ? Wk : Wv;  // [H][D][HS]
    __shared__ float tile[64][65];
    int tid = threadIdx.x, c = tid & 63, rgrp = tid >> 6;
    for (int kc = 0; kc < D_; kc += 64) {
        for (int kk = rgrp; kk < 64; kk += 4)
            tile[kk][c] = W[((size_t)h * D_ + kc + kk) * HS_ + c];
        __syncthreads();
        // Wt[(which*768 + h*64 + ss)*768 + kc + c] = W[h][kc+c][ss] = tile[c][ss]
        for (int ss = rgrp; ss < 64; ss += 4)
            Wt[((size_t)which * D_ + h * HS_ + ss) * D_ + kc + c] = f2bu(tile[c][ss]);
        __syncthreads();
    }
}

// ---------------- Prep: WlmT[v][d] bf16 from Wlm[d][v] f32 ----------------
// grid (500, 12), 256 threads; 64x64 tiles
__global__ void k_transpose_lm(const float* __restrict__ W, ushortT* __restrict__ Wt) {
    __shared__ float tile[64][65];
    int v0 = blockIdx.x * 64, d0 = blockIdx.y * 64;
    int tid = threadIdx.x, c = tid & 63;
    for (int rr = tid >> 6; rr < 64; rr += 4)
        tile[rr][c] = W[(size_t)(d0 + rr) * V_ + v0 + c];
    __syncthreads();
    for (int rr = tid >> 6; rr < 64; rr += 4)
        Wt[(size_t)(v0 + rr) * D_ + d0 + c] = f2bu(tile[c][rr]);
}

// ---------------- Prep: gather masked rows -> xm[384][768] bf16 (zero pad) ----------------
__global__ void k_gather_xm(const float* __restrict__ x2, const int* __restrict__ masked_pos,
                            ushortT* __restrict__ xm) {
    int r = blockIdx.x;      // 0..383
    int tid = threadIdx.x;
    if (r < B_ * NMASK_) {
        int b = r / NMASK_, m = r % NMASK_;
        int t = masked_pos[b * NMASK_ + m];
        for (int d = tid; d < D_; d += 256)
            xm[(size_t)r * D_ + d] = f2bu(x2[((size_t)b * T_ + t) * D_ + d]);
    } else {
        for (int d = tid; d < D_; d += 256)
            xm[(size_t)r * D_ + d] = 0;
    }
}

// ---------------- MFMA 128x128 GEMM tile body ----------------
// A: [M][K] bf16 row-major; Bt: [N][K] bf16 row-major; K = 768.
// 256 threads = 4 waves arranged 2x2, each wave 64x64 = 4x4 16x16x32 fragments.
__device__ __forceinline__ void gemm128_body(const ushortT* __restrict__ A,
                                             const ushortT* __restrict__ Bt,
                                             int m0, int n0,
                                             ushortT As[128][40], ushortT Bs[128][40],
                                             f32x4 acc[4][4]) {
    const int K = D_;
    int tid = threadIdx.x;
    int lane = tid & 63, w = tid >> 6;
    int wr = (w >> 1) * 64, wc = (w & 1) * 64;
    int l16 = lane & 15, lk = lane >> 4;

    #pragma unroll
    for (int i = 0; i < 4; ++i)
        #pragma unroll
        for (int j = 0; j < 4; ++j)
            acc[i][j] = (f32x4){0.f, 0.f, 0.f, 0.f};

    for (int k0 = 0; k0 < K; k0 += 32) {
        __syncthreads();   // protect LDS from previous iteration's readers
        #pragma unroll
        for (int q = 0; q < 2; ++q) {
            int L = tid + q * 256;          // 0..511
            int row = L >> 2, segc = (L & 3) * 8;
            u32x4 da = *(const u32x4*)(A  + (size_t)(m0 + row) * K + k0 + segc);
            *(u32x4*)(&As[row][segc]) = da;
            u32x4 db = *(const u32x4*)(Bt + (size_t)(n0 + row) * K + k0 + segc);
            *(u32x4*)(&Bs[row][segc]) = db;
        }
        __syncthreads();
        short8 a[4], b[4];
        #pragma unroll
        for (int i = 0; i < 4; ++i) {
            a[i] = *(const short8*)(&As[wr + i * 16 + l16][lk * 8]);
            b[i] = *(const short8*)(&Bs[wc + i * 16 + l16][lk * 8]);
        }
        #pragma unroll
        for (int i = 0; i < 4; ++i)
            #pragma unroll
            for (int j = 0; j < 4; ++j)
                acc[i][j] = __builtin_amdgcn_mfma_f32_16x16x32_bf16(a[i], b[j], acc[i][j], 0, 0, 0);
    }
}

// ---------------- QKV GEMM: [8192 x 2304] ----------------
// grid (18, 64): n-tile x, m-tile y. Epilogue scatters to q/k/v bf16.
__global__ void k_gemm_qkv(const ushortT* __restrict__ xb, const ushortT* __restrict__ WcatT,
                           ushortT* __restrict__ qb, ushortT* __restrict__ kb,
                           ushortT* __restrict__ vb) {
    __shared__ ushortT As[128][40];
    __shared__ ushortT Bs[128][40];
    f32x4 acc[4][4];
    int n0 = blockIdx.x * 128, m0 = blockIdx.y * 128;
    gemm128_body(xb, WcatT, m0, n0, As, Bs, acc);

    int lane = threadIdx.x & 63, w = threadIdx.x >> 6;
    int wr = (w >> 1) * 64, wc = (w & 1) * 64;
    int l16 = lane & 15, lk = lane >> 4;
    #pragma unroll
    for (int j = 0; j < 4; ++j) {
        int n = n0 + wc + j * 16 + l16;
        int which = n / D_;
        int rem = n - which * D_;
        int h = rem >> 6, s = rem & 63;
        ushortT* outp = (which == 0) ? qb : (which == 1) ? kb : vb;
        #pragma unroll
        for (int i = 0; i < 4; ++i) {
            #pragma unroll
            for (int r = 0; r < 4; ++r) {
                int m = m0 + wr + i * 16 + lk * 4 + r;
                int b = m >> 9, t = m & (T_ - 1);
                outp[((size_t)(b * H_ + h) * T_ + t) * HS_ + s] = f2bu(acc[i][j][r]);
            }
        }
    }
}

// ---------------- LM GEMM: [384 x 32000] (rows >= 320 padded) ----------------
// grid (3, 250): m-tile x (fast, shares B tile in L2), n-tile y.
__global__ void k_gemm_lm(const ushortT* __restrict__ xm, const ushortT* __restrict__ WlmT,
                          const float* __restrict__ blm, float* __restrict__ out) {
    __shared__ ushortT As[128][40];
    __shared__ ushortT Bs[128][40];
    f32x4 acc[4][4];
    int m0 = blockIdx.x * 128, n0 = blockIdx.y * 128;
    gemm128_body(xm, WlmT, m0, n0, As, Bs, acc);

    int lane = threadIdx.x & 63, w = threadIdx.x >> 6;
    int wr = (w >> 1) * 64, wc = (w & 1) * 64;
    int l16 = lane & 15, lk = lane >> 4;
    #pragma unroll
    for (int j = 0; j < 4; ++j) {
        int n = n0 + wc + j * 16 + l16;
        float bias = blm[n];
        #pragma unroll
        for (int i = 0; i < 4; ++i) {
            #pragma unroll
            for (int r = 0; r < 4; ++r) {
                int m = m0 + wr + i * 16 + lk * 4 + r;
                if (m < B_ * NMASK_)
                    out[(size_t)m * V_ + n] = acc[i][j][r] + bias;
            }
        }
    }
}

// ---------------- Attention (one wave per (b,h,t)) — unchanged ----------------
__global__ void k_attn(const bf16* __restrict__ q, const bf16* __restrict__ k,
                       const bf16* __restrict__ v, const int* __restrict__ attn_mask,
                       float* __restrict__ x2) {
    int idx = blockIdx.x;           // (b*H + h)*T + t
    int t  = idx % T_;
    int bh = idx / T_;
    int h  = bh % H_;
    int b  = bh / H_;
    int lane = threadIdx.x;         // 0..63

    __shared__ float qs[HS_];
    __shared__ float p[T_];

    const bf16* qrow = q + ((size_t)bh * T_ + t) * HS_;
    qs[lane] = b2f(qrow[lane]);
    __syncthreads();

    bool masked = (attn_mask[b * T_ + t] == 0);
    const bf16* kb = k + (size_t)bh * T_ * HS_;

    float sc[8];
    float mx = -1e30f;
    #pragma unroll
    for (int i = 0; i < 8; ++i) {
        int u = i * 64 + lane;
        const bf16* krow = kb + (size_t)u * HS_;
        float acc = 0.f;
        #pragma unroll 8
        for (int ss = 0; ss < HS_; ++ss) acc += qs[ss] * b2f(krow[ss]);
        sc[i] = masked ? -1e-11f : acc * 0.125f;
        mx = fmaxf(mx, sc[i]);
    }
    #pragma unroll
    for (int o = 32; o > 0; o >>= 1) mx = fmaxf(mx, __shfl_xor(mx, o));
    float lsum = 0.f;
    #pragma unroll
    for (int i = 0; i < 8; ++i) { sc[i] = expf(sc[i] - mx); lsum += sc[i]; }
    #pragma unroll
    for (int o = 32; o > 0; o >>= 1) lsum += __shfl_xor(lsum, o);
    float inv = 1.0f / lsum;
    #pragma unroll
    for (int i = 0; i < 8; ++i) p[i * 64 + lane] = sc[i] * inv;
    __syncthreads();

    const bf16* vb = v + (size_t)bh * T_ * HS_;
    float acc = 0.f;
    for (int u = 0; u < T_; ++u) acc += p[u] * b2f(vb[(size_t)u * HS_ + lane]);
    x2[((size_t)b * T_ + t) * D_ + h * HS_ + lane] = acc;
}

// ---------------- Classifier head ----------------
__global__ void k_cls(const float* __restrict__ x2, const float* __restrict__ Wc,
                      const float* __restrict__ bc, float* __restrict__ out) {
    int i = threadIdx.x;
    if (i >= B_ * 2) return;
    int b = i >> 1, c = i & 1;
    float acc = bc[c];
    for (int d = 0; d < D_; ++d)
        acc += x2[(size_t)b * T_ * D_ + d] * Wc[d * 2 + c];
    out[i] = acc;
}

extern "C" void kernel_launch(void* const* d_in, const int* in_sizes, int n_in,
                              void* d_out, int out_size, void* d_ws, size_t ws_size,
                              hipStream_t stream) {
    const int* seq        = (const int*)d_in[0];
    const int* seg        = (const int*)d_in[1];
    const int* attn_mask  = (const int*)d_in[2];
    const int* masked_pos = (const int*)d_in[3];
    const float* tok  = (const float*)d_in[4];
    const float* sege = (const float*)d_in[5];
    const float* pos  = (const float*)d_in[6];
    const float* ln_g = (const float*)d_in[7];
    const float* ln_b = (const float*)d_in[8];
    const float* Wq   = (const float*)d_in[9];
    const float* Wk   = (const float*)d_in[10];
    const float* Wv   = (const float*)d_in[11];
    const float* Wlm  = (const float*)d_in[12];
    const float* blm  = (const float*)d_in[13];
    const float* Wc   = (const float*)d_in[14];
    const float* bc   = (const float*)d_in[15];

    float* out_lm  = (float*)d_out;                       // [B, NMASK, V]
    float* out_cls = out_lm + (size_t)B_ * NMASK_ * V_;   // [B, 2]

    const size_t XSZ = (size_t)B_ * T_ * D_;              // 6,291,456
    float* ws = (float*)d_ws;
    float*   x2   = ws;                                   // f32, 25.2 MB
    ushortT* base = (ushortT*)(ws + XSZ);                 // bf16 region
    ushortT* xb    = base;                                // [8192][768]
    ushortT* qb    = base + XSZ;
    ushortT* kb    = base + 2 * XSZ;
    ushortT* vb    = base + 3 * XSZ;
    ushortT* WcatT = base + 4 * XSZ;                      // [2304][768]
    // After attention, xb/q/k/v/WcatT are dead; reuse for LM buffers:
    ushortT* WlmT  = base;                                // [32000][768] = 24,576,000
    ushortT* xm    = base + (size_t)V_ * D_;              // [384][768]

    k_embed_ln<<<B_ * T_, 256, 0, stream>>>(seq, seg, tok, sege, pos, ln_g, ln_b, xb);
    k_prep_wqkv<<<3 * H_, 256, 0, stream>>>(Wq, Wk, Wv, WcatT);
    k_gemm_qkv<<<dim3(18, 64), 256, 0, stream>>>(xb, WcatT, qb, kb, vb);
    k_attn<<<B_ * H_ * T_, 64, 0, stream>>>((const bf16*)qb, (const bf16*)kb,
                                            (const bf16*)vb, attn_mask, x2);
    k_transpose_lm<<<dim3(V_ / 64, D_ / 64), 256, 0, stream>>>(Wlm, WlmT);
    k_gather_xm<<<384, 256, 0, stream>>>(x2, masked_pos, xm);
    k_gemm_lm<<<dim3(3, 250), 256, 0, stream>>>(xm, WlmT, blm, out_lm);
    k_cls<<<1, 64, 0, stream>>>(x2, Wc, bc, out_cls);
}

// Round 5
// 230.678 us; speedup vs baseline: 20.6788x; 7.0648x over previous
//
#include <hip/hip_runtime.h>
#include <hip/hip_bf16.h>

#define V_     32000
#define NSEG_  2
#define MAXLEN_ 512
#define D_     768
#define H_     12
#define HS_    64
#define B_     16
#define T_     512
#define NMASK_ 20
#define LN_EPS_ 1e-5f

typedef __hip_bfloat16 bf16;
typedef unsigned short ushortT;
typedef __attribute__((ext_vector_type(8))) short short8;
typedef __attribute__((ext_vector_type(4))) float f32x4;
typedef __attribute__((ext_vector_type(4))) unsigned int u32x4;

__device__ __forceinline__ float b2f(bf16 x) { return __bfloat162float(x); }
__device__ __forceinline__ ushortT f2bu(float f) {
    bf16 h = __float2bfloat16(f);
    return *reinterpret_cast<ushortT*>(&h);
}

// ---------------- Kernel 1: embedding gather + LayerNorm -> xb (bf16) ----------------
__global__ void k_embed_ln(const int* __restrict__ seq, const int* __restrict__ seg,
                           const float* __restrict__ tok, const float* __restrict__ sege,
                           const float* __restrict__ pos, const float* __restrict__ g,
                           const float* __restrict__ bb, ushortT* __restrict__ xb) {
    int row = blockIdx.x;          // b*T + t
    int t = row % T_;
    int tid = threadIdx.x;
    __shared__ float sbuf[D_];
    __shared__ float wsum[4], wsq[4];

    int sidx = seq[row];
    int gidx = seg[row];

    float lsum = 0.f, lsq = 0.f;
    for (int j = tid; j < D_; j += 256) {
        float e = tok[(size_t)sidx * D_ + j] + sege[(size_t)gidx * D_ + j] + pos[(size_t)t * D_ + j];
        sbuf[j] = e;
        lsum += e;
        lsq  += e * e;
    }
    #pragma unroll
    for (int o = 32; o > 0; o >>= 1) {
        lsum += __shfl_down(lsum, o);
        lsq  += __shfl_down(lsq, o);
    }
    if ((tid & 63) == 0) { wsum[tid >> 6] = lsum; wsq[tid >> 6] = lsq; }
    __syncthreads();
    float s  = wsum[0] + wsum[1] + wsum[2] + wsum[3];
    float sq = wsq[0] + wsq[1] + wsq[2] + wsq[3];
    float mean = s * (1.0f / D_);
    float var  = sq * (1.0f / D_) - mean * mean;
    float rstd = rsqrtf(var + LN_EPS_);
    for (int j = tid; j < D_; j += 256) {
        xb[(size_t)row * D_ + j] = f2bu((sbuf[j] - mean) * rstd * g[j] + bb[j]);
    }
}

// ---------------- Prep: WcatT[n][k] bf16, n = which*768 + h*64 + s ----------------
__global__ void k_prep_wqkv(const float* __restrict__ Wq, const float* __restrict__ Wk,
                            const float* __restrict__ Wv, ushortT* __restrict__ Wt) {
    int blk = blockIdx.x;
    int which = blk / H_, h = blk % H_;
    const float* W = (which == 0) ? Wq : (which == 1) ? Wk : Wv;  // [H][D][HS]
    __shared__ float tile[64][65];
    int tid = threadIdx.x, c = tid & 63, rgrp = tid >> 6;
    for (int kc = 0; kc < D_; kc += 64) {
        for (int kk = rgrp; kk < 64; kk += 4)
            tile[kk][c] = W[((size_t)h * D_ + kc + kk) * HS_ + c];
        __syncthreads();
        for (int ss = rgrp; ss < 64; ss += 4)
            Wt[((size_t)which * D_ + h * HS_ + ss) * D_ + kc + c] = f2bu(tile[c][ss]);
        __syncthreads();
    }
}

// ---------------- Prep: WlmT[v][d] bf16 from Wlm[d][v] f32 ----------------
__global__ void k_transpose_lm(const float* __restrict__ W, ushortT* __restrict__ Wt) {
    __shared__ float tile[64][65];
    int v0 = blockIdx.x * 64, d0 = blockIdx.y * 64;
    int tid = threadIdx.x, c = tid & 63;
    for (int rr = tid >> 6; rr < 64; rr += 4)
        tile[rr][c] = W[(size_t)(d0 + rr) * V_ + v0 + c];
    __syncthreads();
    for (int rr = tid >> 6; rr < 64; rr += 4)
        Wt[(size_t)(v0 + rr) * D_ + d0 + c] = f2bu(tile[c][rr]);
}

// ---------------- Prep: gather masked rows -> xm[384][768] bf16 (zero pad) ----------------
__global__ void k_gather_xm(const float* __restrict__ x2, const int* __restrict__ masked_pos,
                            ushortT* __restrict__ xm) {
    int r = blockIdx.x;      // 0..383
    int tid = threadIdx.x;
    if (r < B_ * NMASK_) {
        int b = r / NMASK_, m = r % NMASK_;
        int t = masked_pos[b * NMASK_ + m];
        for (int d = tid; d < D_; d += 256)
            xm[(size_t)r * D_ + d] = f2bu(x2[((size_t)b * T_ + t) * D_ + d]);
    } else {
        for (int d = tid; d < D_; d += 256)
            xm[(size_t)r * D_ + d] = 0;
    }
}

// ---------------- MFMA 128x128 GEMM tile body ----------------
__device__ __forceinline__ void gemm128_body(const ushortT* __restrict__ A,
                                             const ushortT* __restrict__ Bt,
                                             int m0, int n0,
                                             ushortT As[128][40], ushortT Bs[128][40],
                                             f32x4 acc[4][4]) {
    const int K = D_;
    int tid = threadIdx.x;
    int lane = tid & 63, w = tid >> 6;
    int wr = (w >> 1) * 64, wc = (w & 1) * 64;
    int l16 = lane & 15, lk = lane >> 4;

    #pragma unroll
    for (int i = 0; i < 4; ++i)
        #pragma unroll
        for (int j = 0; j < 4; ++j)
            acc[i][j] = (f32x4){0.f, 0.f, 0.f, 0.f};

    for (int k0 = 0; k0 < K; k0 += 32) {
        __syncthreads();
        #pragma unroll
        for (int q = 0; q < 2; ++q) {
            int L = tid + q * 256;          // 0..511
            int row = L >> 2, segc = (L & 3) * 8;
            u32x4 da = *(const u32x4*)(A  + (size_t)(m0 + row) * K + k0 + segc);
            *(u32x4*)(&As[row][segc]) = da;
            u32x4 db = *(const u32x4*)(Bt + (size_t)(n0 + row) * K + k0 + segc);
            *(u32x4*)(&Bs[row][segc]) = db;
        }
        __syncthreads();
        short8 a[4], b[4];
        #pragma unroll
        for (int i = 0; i < 4; ++i) {
            a[i] = *(const short8*)(&As[wr + i * 16 + l16][lk * 8]);
            b[i] = *(const short8*)(&Bs[wc + i * 16 + l16][lk * 8]);
        }
        #pragma unroll
        for (int i = 0; i < 4; ++i)
            #pragma unroll
            for (int j = 0; j < 4; ++j)
                acc[i][j] = __builtin_amdgcn_mfma_f32_16x16x32_bf16(a[i], b[j], acc[i][j], 0, 0, 0);
    }
}

// ---------------- QKV GEMM: [8192 x 2304] ----------------
__global__ void k_gemm_qkv(const ushortT* __restrict__ xb, const ushortT* __restrict__ WcatT,
                           ushortT* __restrict__ qb, ushortT* __restrict__ kb,
                           ushortT* __restrict__ vb) {
    __shared__ ushortT As[128][40];
    __shared__ ushortT Bs[128][40];
    f32x4 acc[4][4];
    int n0 = blockIdx.x * 128, m0 = blockIdx.y * 128;
    gemm128_body(xb, WcatT, m0, n0, As, Bs, acc);

    int lane = threadIdx.x & 63, w = threadIdx.x >> 6;
    int wr = (w >> 1) * 64, wc = (w & 1) * 64;
    int l16 = lane & 15, lk = lane >> 4;
    #pragma unroll
    for (int j = 0; j < 4; ++j) {
        int n = n0 + wc + j * 16 + l16;
        int which = n / D_;
        int rem = n - which * D_;
        int h = rem >> 6, s = rem & 63;
        ushortT* outp = (which == 0) ? qb : (which == 1) ? kb : vb;
        #pragma unroll
        for (int i = 0; i < 4; ++i) {
            #pragma unroll
            for (int r = 0; r < 4; ++r) {
                int m = m0 + wr + i * 16 + lk * 4 + r;
                int b = m >> 9, t = m & (T_ - 1);
                outp[((size_t)(b * H_ + h) * T_ + t) * HS_ + s] = f2bu(acc[i][j][r]);
            }
        }
    }
}

// ---------------- LM GEMM: [384 x 32000] ----------------
__global__ void k_gemm_lm(const ushortT* __restrict__ xm, const ushortT* __restrict__ WlmT,
                          const float* __restrict__ blm, float* __restrict__ out) {
    __shared__ ushortT As[128][40];
    __shared__ ushortT Bs[128][40];
    f32x4 acc[4][4];
    int m0 = blockIdx.x * 128, n0 = blockIdx.y * 128;
    gemm128_body(xm, WlmT, m0, n0, As, Bs, acc);

    int lane = threadIdx.x & 63, w = threadIdx.x >> 6;
    int wr = (w >> 1) * 64, wc = (w & 1) * 64;
    int l16 = lane & 15, lk = lane >> 4;
    #pragma unroll
    for (int j = 0; j < 4; ++j) {
        int n = n0 + wc + j * 16 + l16;
        float bias = blm[n];
        #pragma unroll
        for (int i = 0; i < 4; ++i) {
            #pragma unroll
            for (int r = 0; r < 4; ++r) {
                int m = m0 + wr + i * 16 + lk * 4 + r;
                if (m < B_ * NMASK_)
                    out[(size_t)m * V_ + n] = acc[i][j][r] + bias;
            }
        }
    }
}

// ---------------- Flash-style MFMA attention ----------------
// grid = 192 (b,h) * 4 q-tiles; 256 threads = 4 waves; wave w owns q-rows [w*32, w*32+32).
// LDS tiles are 64 elements wide -> inner dim 72 (64 + 8 pad).
__global__ __launch_bounds__(256, 2)
void k_attn_mfma(const ushortT* __restrict__ qb, const ushortT* __restrict__ kb,
                 const ushortT* __restrict__ vb, const int* __restrict__ attn_mask,
                 float* __restrict__ x2) {
    int blk = blockIdx.x;
    int qt = blk & 3, bh = blk >> 2;
    int b = bh / H_, h = bh % H_;
    int tid = threadIdx.x, lane = tid & 63, w = tid >> 6;
    int l16 = lane & 15, lk = lane >> 4;

    __shared__ ushortT Qs[128][72];
    __shared__ ushortT Ks[64][72];
    __shared__ ushortT Vts[64][72];     // Vts[d][key]
    __shared__ ushortT Ps[4][32][72];   // per-wave P tile (32 q-rows x 64 keys)
    __shared__ float mskS[128];

    // ---- stage Q tile (once) + mask scale ----
    const ushortT* Qg = qb + ((size_t)bh * T_ + qt * 128) * HS_;
    #pragma unroll
    for (int rr = 0; rr < 2; ++rr) {
        int r = (tid >> 2) + rr * 64;
        int c = (tid & 3) * 16;
        *(u32x4*)(&Qs[r][c])     = *(const u32x4*)(Qg + (size_t)r * HS_ + c);
        *(u32x4*)(&Qs[r][c + 8]) = *(const u32x4*)(Qg + (size_t)r * HS_ + c + 8);
    }
    if (tid < 128)
        mskS[tid] = attn_mask[b * T_ + qt * 128 + tid] ? 0.125f : 0.0f;
    __syncthreads();

    // ---- hoist Q fragments (constant across key tiles) ----
    short8 aq[2][2];
    #pragma unroll
    for (int i = 0; i < 2; ++i)
        #pragma unroll
        for (int ks = 0; ks < 2; ++ks)
            aq[i][ks] = *(const short8*)(&Qs[w * 32 + i * 16 + l16][ks * 32 + lk * 8]);

    float m_run[2][4], l_run[2][4];
    f32x4 accO[2][4];
    #pragma unroll
    for (int i = 0; i < 2; ++i)
        #pragma unroll
        for (int r = 0; r < 4; ++r) { m_run[i][r] = -1e30f; l_run[i][r] = 0.f; }
    #pragma unroll
    for (int i = 0; i < 2; ++i)
        #pragma unroll
        for (int j = 0; j < 4; ++j)
            accO[i][j] = (f32x4){0.f, 0.f, 0.f, 0.f};

    for (int kt = 0; kt < 8; ++kt) {
        __syncthreads();
        // ---- stage K tile (coalesced) ----
        {
            int r = tid >> 2, c = (tid & 3) * 16;
            const ushortT* Kg = kb + ((size_t)bh * T_ + kt * 64 + r) * HS_ + c;
            *(u32x4*)(&Ks[r][c])     = *(const u32x4*)(Kg);
            *(u32x4*)(&Ks[r][c + 8]) = *(const u32x4*)(Kg + 8);
        }
        // ---- stage V tile transposed: lane = key row, wave picks 16 d-cols ----
        {
            int r = lane;                   // key within tile
            int c = w * 16;                 // d col base
            const ushortT* Vg = vb + ((size_t)bh * T_ + kt * 64 + r) * HS_ + c;
            short8 v0 = *(const short8*)(Vg);
            short8 v1 = *(const short8*)(Vg + 8);
            #pragma unroll
            for (int e = 0; e < 8; ++e) Vts[c + e][r]     = (ushortT)v0[e];
            #pragma unroll
            for (int e = 0; e < 8; ++e) Vts[c + 8 + e][r] = (ushortT)v1[e];
        }
        __syncthreads();

        // ---- S = Q K^T (per wave: 32 q x 64 k) ----
        f32x4 accS[2][4];
        #pragma unroll
        for (int i = 0; i < 2; ++i)
            #pragma unroll
            for (int j = 0; j < 4; ++j)
                accS[i][j] = (f32x4){0.f, 0.f, 0.f, 0.f};
        #pragma unroll
        for (int ks = 0; ks < 2; ++ks) {
            short8 bk[4];
            #pragma unroll
            for (int j = 0; j < 4; ++j)
                bk[j] = *(const short8*)(&Ks[j * 16 + l16][ks * 32 + lk * 8]);
            #pragma unroll
            for (int i = 0; i < 2; ++i)
                #pragma unroll
                for (int j = 0; j < 4; ++j)
                    accS[i][j] = __builtin_amdgcn_mfma_f32_16x16x32_bf16(aq[i][ks], bk[j], accS[i][j], 0, 0, 0);
        }

        // ---- online softmax (row = 16-lane group) + P -> LDS ----
        #pragma unroll
        for (int i = 0; i < 2; ++i) {
            #pragma unroll
            for (int r = 0; r < 4; ++r) {
                int rowl = i * 16 + lk * 4 + r;
                float msk = mskS[w * 32 + rowl];
                float s0 = accS[i][0][r] * msk;
                float s1 = accS[i][1][r] * msk;
                float s2 = accS[i][2][r] * msk;
                float s3 = accS[i][3][r] * msk;
                float vmax = fmaxf(fmaxf(s0, s1), fmaxf(s2, s3));
                #pragma unroll
                for (int off = 1; off < 16; off <<= 1)
                    vmax = fmaxf(vmax, __shfl_xor(vmax, off));
                float mold = m_run[i][r];
                float mn = fmaxf(mold, vmax);
                float scale = __expf(mold - mn);
                float p0 = __expf(s0 - mn), p1 = __expf(s1 - mn);
                float p2 = __expf(s2 - mn), p3 = __expf(s3 - mn);
                float rsum = (p0 + p1) + (p2 + p3);
                #pragma unroll
                for (int off = 1; off < 16; off <<= 1)
                    rsum += __shfl_xor(rsum, off);
                l_run[i][r] = l_run[i][r] * scale + rsum;
                m_run[i][r] = mn;
                accO[i][0][r] *= scale;
                accO[i][1][r] *= scale;
                accO[i][2][r] *= scale;
                accO[i][3][r] *= scale;
                Ps[w][rowl][0 * 16 + l16] = f2bu(p0);
                Ps[w][rowl][1 * 16 + l16] = f2bu(p1);
                Ps[w][rowl][2 * 16 + l16] = f2bu(p2);
                Ps[w][rowl][3 * 16 + l16] = f2bu(p3);
            }
        }

        // ---- O += P V (A = P from LDS, B = Vts) ----
        #pragma unroll
        for (int ks2 = 0; ks2 < 2; ++ks2) {
            short8 ap[2], bv[4];
            #pragma unroll
            for (int i = 0; i < 2; ++i)
                ap[i] = *(const short8*)(&Ps[w][i * 16 + l16][ks2 * 32 + lk * 8]);
            #pragma unroll
            for (int j = 0; j < 4; ++j)
                bv[j] = *(const short8*)(&Vts[j * 16 + l16][ks2 * 32 + lk * 8]);
            #pragma unroll
            for (int i = 0; i < 2; ++i)
                #pragma unroll
                for (int j = 0; j < 4; ++j)
                    accO[i][j] = __builtin_amdgcn_mfma_f32_16x16x32_bf16(ap[i], bv[j], accO[i][j], 0, 0, 0);
        }
    }

    // ---- epilogue: normalize and write x2 (f32) ----
    #pragma unroll
    for (int i = 0; i < 2; ++i) {
        #pragma unroll
        for (int r = 0; r < 4; ++r) {
            float inv = 1.0f / l_run[i][r];
            int t = qt * 128 + w * 32 + i * 16 + lk * 4 + r;
            float* outp = x2 + ((size_t)b * T_ + t) * D_ + h * HS_;
            #pragma unroll
            for (int j = 0; j < 4; ++j)
                outp[j * 16 + l16] = accO[i][j][r] * inv;
        }
    }
}

// ---------------- Classifier head ----------------
__global__ void k_cls(const float* __restrict__ x2, const float* __restrict__ Wc,
                      const float* __restrict__ bc, float* __restrict__ out) {
    int i = threadIdx.x;
    if (i >= B_ * 2) return;
    int b = i >> 1, c = i & 1;
    float acc = bc[c];
    for (int d = 0; d < D_; ++d)
        acc += x2[(size_t)b * T_ * D_ + d] * Wc[d * 2 + c];
    out[i] = acc;
}

extern "C" void kernel_launch(void* const* d_in, const int* in_sizes, int n_in,
                              void* d_out, int out_size, void* d_ws, size_t ws_size,
                              hipStream_t stream) {
    const int* seq        = (const int*)d_in[0];
    const int* seg        = (const int*)d_in[1];
    const int* attn_mask  = (const int*)d_in[2];
    const int* masked_pos = (const int*)d_in[3];
    const float* tok  = (const float*)d_in[4];
    const float* sege = (const float*)d_in[5];
    const float* pos  = (const float*)d_in[6];
    const float* ln_g = (const float*)d_in[7];
    const float* ln_b = (const float*)d_in[8];
    const float* Wq   = (const float*)d_in[9];
    const float* Wk   = (const float*)d_in[10];
    const float* Wv   = (const float*)d_in[11];
    const float* Wlm  = (const float*)d_in[12];
    const float* blm  = (const float*)d_in[13];
    const float* Wc   = (const float*)d_in[14];
    const float* bc   = (const float*)d_in[15];

    float* out_lm  = (float*)d_out;                       // [B, NMASK, V]
    float* out_cls = out_lm + (size_t)B_ * NMASK_ * V_;   // [B, 2]

    const size_t XSZ = (size_t)B_ * T_ * D_;              // 6,291,456
    float* ws = (float*)d_ws;
    float*   x2   = ws;                                   // f32, 25.2 MB
    ushortT* base = (ushortT*)(ws + XSZ);                 // bf16 region
    ushortT* xb    = base;                                // [8192][768]
    ushortT* qb    = base + XSZ;
    ushortT* kb    = base + 2 * XSZ;
    ushortT* vb    = base + 3 * XSZ;
    ushortT* WcatT = base + 4 * XSZ;                      // [2304][768]
    // After attention, xb/q/k/v/WcatT are dead; reuse for LM buffers:
    ushortT* WlmT  = base;                                // [32000][768]
    ushortT* xm    = base + (size_t)V_ * D_;              // [384][768]

    k_embed_ln<<<B_ * T_, 256, 0, stream>>>(seq, seg, tok, sege, pos, ln_g, ln_b, xb);
    k_prep_wqkv<<<3 * H_, 256, 0, stream>>>(Wq, Wk, Wv, WcatT);
    k_gemm_qkv<<<dim3(18, 64), 256, 0, stream>>>(xb, WcatT, qb, kb, vb);
    k_attn_mfma<<<192 * 4, 256, 0, stream>>>(qb, kb, vb, attn_mask, x2);
    k_transpose_lm<<<dim3(V_ / 64, D_ / 64), 256, 0, stream>>>(Wlm, WlmT);
    k_gather_xm<<<384, 256, 0, stream>>>(x2, masked_pos, xm);
    k_gemm_lm<<<dim3(3, 250), 256, 0, stream>>>(xm, WlmT, blm, out_lm);
    k_cls<<<1, 64, 0, stream>>>(x2, Wc, bc, out_cls);
}